// Round 3
// baseline (371.751 us; speedup 1.0000x reference)
//
#include <hip/hip_runtime.h>

// FWHT, natural (Sylvester) order: out[c] = sum_j (-1)^popcount(c&j) x[j]
// D = 4096 = 16*16*16 -> three in-register W16 phases + LDS digit swaps.
// v2b: third LDS exchange so stores are float4; nontemporal stores via native
// clang vector type (HIP float4 struct is rejected by the builtin).

typedef float f32x4 __attribute__((ext_vector_type(4)));

__device__ __forceinline__ void wht16(float v[16]) {
#pragma unroll
    for (int h = 1; h < 16; h <<= 1) {
#pragma unroll
        for (int i = 0; i < 16; i++) {
            if ((i & h) == 0) {
                float a = v[i];
                float b = v[i ^ h];
                v[i]     = a + b;
                v[i ^ h] = a - b;
            }
        }
    }
}

__global__ __launch_bounds__(256) void fwht4096_kernel(const float* __restrict__ in,
                                                       float* __restrict__ out) {
    // padded LDS: logical (b2,b1,b0) stored at (b2*16+b1)*17 + b0
    __shared__ float lds[256 * 17];

    const int row = blockIdx.x;
    const int t   = threadIdx.x;

    float v[16];

    // ---- load: thread t owns j = t*16 + r (contiguous 64B -> 4x float4) ----
    const f32x4* p4 = (const f32x4*)(in + (size_t)row * 4096 + t * 16);
#pragma unroll
    for (int q = 0; q < 4; q++) {
        f32x4 f = p4[q];
        v[4 * q + 0] = f.x;
        v[4 * q + 1] = f.y;
        v[4 * q + 2] = f.z;
        v[4 * q + 3] = f.w;
    }

    // ---- phase 1: W16 over bits 0-3 (b0) ----
    wht16(v);

    // ---- exchange 1: thread t=(b2,b1), regs=b0  ->  thread (b2,b0), regs=b1 ----
#pragma unroll
    for (int r = 0; r < 16; r++) lds[t * 17 + r] = v[r];
    __syncthreads();

    const int u_hi = t >> 4;   // b2
    const int u_lo = t & 15;   // b0
#pragma unroll
    for (int k = 0; k < 16; k++) v[k] = lds[(u_hi * 16 + k) * 17 + u_lo];

    // ---- phase 2: W16 over bits 4-7 (b1) ----
    wht16(v);

    // ---- exchange 2: write back to the exact slots this thread read (race-free
    //      without a pre-barrier), then re-read along b2 ----
#pragma unroll
    for (int k = 0; k < 16; k++) lds[(u_hi * 16 + k) * 17 + u_lo] = v[k];
    __syncthreads();

#pragma unroll
    for (int m = 0; m < 16; m++) v[m] = lds[(m * 16 + u_hi) * 17 + u_lo];

    // ---- phase 3: W16 over bits 8-11 (b2); thread now = (b1,b0) ----
    wht16(v);

    // ---- exchange 3: each slot's phase-3 reader == its writer (thread (u_hi,u_lo)
    //      for all m), and every write value depends on all 16 reads, so no
    //      pre-barrier needed. Then gather 16 contiguous j = t*16 + r. ----
#pragma unroll
    for (int m = 0; m < 16; m++) lds[(m * 16 + u_hi) * 17 + u_lo] = v[m];
    __syncthreads();

#pragma unroll
    for (int r = 0; r < 16; r++) v[r] = lds[t * 17 + r];

    // ---- store: 4x float4, nontemporal (don't evict the L3-resident input) ----
    f32x4* op4 = (f32x4*)(out + (size_t)row * 4096 + t * 16);
#pragma unroll
    for (int q = 0; q < 4; q++) {
        f32x4 f = { v[4 * q + 0], v[4 * q + 1], v[4 * q + 2], v[4 * q + 3] };
        __builtin_nontemporal_store(f, op4 + q);
    }
}

extern "C" void kernel_launch(void* const* d_in, const int* in_sizes, int n_in,
                              void* d_out, int out_size, void* d_ws, size_t ws_size,
                              hipStream_t stream) {
    const float* x = (const float*)d_in[0];
    float* out     = (float*)d_out;
    const int rows = in_sizes[0] / 4096;   // 16384
    fwht4096_kernel<<<dim3(rows), dim3(256), 0, stream>>>(x, out);
}

// Round 4
// 111.776 us; speedup vs baseline: 3.3258x; 3.3258x over previous
//
#include <hip/hip_runtime.h>

// FWHT, natural (Sylvester) order: out[c] = sum_j (-1)^popcount(c&j) x[j]
// D = 4096 = 16*16*16 -> three in-register W16 phases + LDS digit swaps.
// v3: third LDS exchange so stores are float4 (dwordx4). NO nontemporal hint:
// on gfx950 nt stores caused 2.7x HBM write amplification (R3 counters).

typedef float f32x4 __attribute__((ext_vector_type(4)));

__device__ __forceinline__ void wht16(float v[16]) {
#pragma unroll
    for (int h = 1; h < 16; h <<= 1) {
#pragma unroll
        for (int i = 0; i < 16; i++) {
            if ((i & h) == 0) {
                float a = v[i];
                float b = v[i ^ h];
                v[i]     = a + b;
                v[i ^ h] = a - b;
            }
        }
    }
}

__global__ __launch_bounds__(256) void fwht4096_kernel(const float* __restrict__ in,
                                                       float* __restrict__ out) {
    // padded LDS: logical (b2,b1,b0) stored at (b2*16+b1)*17 + b0
    __shared__ float lds[256 * 17];

    const int row = blockIdx.x;
    const int t   = threadIdx.x;

    float v[16];

    // ---- load: thread t owns j = t*16 + r (contiguous 64B -> 4x float4) ----
    const f32x4* p4 = (const f32x4*)(in + (size_t)row * 4096 + t * 16);
#pragma unroll
    for (int q = 0; q < 4; q++) {
        f32x4 f = p4[q];
        v[4 * q + 0] = f.x;
        v[4 * q + 1] = f.y;
        v[4 * q + 2] = f.z;
        v[4 * q + 3] = f.w;
    }

    // ---- phase 1: W16 over bits 0-3 (b0) ----
    wht16(v);

    // ---- exchange 1: thread t=(b2,b1), regs=b0  ->  thread (b2,b0), regs=b1 ----
#pragma unroll
    for (int r = 0; r < 16; r++) lds[t * 17 + r] = v[r];
    __syncthreads();

    const int u_hi = t >> 4;   // b2
    const int u_lo = t & 15;   // b0
#pragma unroll
    for (int k = 0; k < 16; k++) v[k] = lds[(u_hi * 16 + k) * 17 + u_lo];

    // ---- phase 2: W16 over bits 4-7 (b1) ----
    wht16(v);

    // ---- exchange 2: write back to the exact slots this thread read (race-free
    //      without a pre-barrier), then re-read along b2 ----
#pragma unroll
    for (int k = 0; k < 16; k++) lds[(u_hi * 16 + k) * 17 + u_lo] = v[k];
    __syncthreads();

#pragma unroll
    for (int m = 0; m < 16; m++) v[m] = lds[(m * 16 + u_hi) * 17 + u_lo];

    // ---- phase 3: W16 over bits 8-11 (b2); thread now = (b1,b0) ----
    wht16(v);

    // ---- exchange 3: each slot's phase-3 reader == its writer (thread (u_hi,u_lo)
    //      for all m), and every write value depends on all 16 reads, so no
    //      pre-barrier needed. Then gather 16 contiguous j = t*16 + r. ----
#pragma unroll
    for (int m = 0; m < 16; m++) lds[(m * 16 + u_hi) * 17 + u_lo] = v[m];
    __syncthreads();

#pragma unroll
    for (int r = 0; r < 16; r++) v[r] = lds[t * 17 + r];

    // ---- store: 4x dwordx4, normal cached path ----
    f32x4* op4 = (f32x4*)(out + (size_t)row * 4096 + t * 16);
#pragma unroll
    for (int q = 0; q < 4; q++) {
        f32x4 f = { v[4 * q + 0], v[4 * q + 1], v[4 * q + 2], v[4 * q + 3] };
        op4[q] = f;
    }
}

extern "C" void kernel_launch(void* const* d_in, const int* in_sizes, int n_in,
                              void* d_out, int out_size, void* d_ws, size_t ws_size,
                              hipStream_t stream) {
    const float* x = (const float*)d_in[0];
    float* out     = (float*)d_out;
    const int rows = in_sizes[0] / 4096;   // 16384
    fwht4096_kernel<<<dim3(rows), dim3(256), 0, stream>>>(x, out);
}

// Round 6
// 101.227 us; speedup vs baseline: 3.6724x; 1.1042x over previous
//
#include <hip/hip_runtime.h>

// FWHT 4096, natural (Sylvester) order. v5: single LDS exchange.
// Decomposition per row (j = b11..b0, thread t = w[2]|l45[2]|l23[2]|l01[2]):
//   load:   thread t holds j = t*16 + r  (regs r = b0-3)
//   A: W16 in regs (b0-3), then W4 over b4-5 via DPP quad_perm (VALU pipe)
//   one LDS exchange -> thread holds j = l45*1024 + r*64 + w*16 + l23*4 + l01
//   B: W16 in regs (b6-9), W2 over b10 via ds_swizzle xor16,
//      W2 over b11 via __shfl_xor 32 (v4's raw v_permlane32_swap asm killed
//      the kernel -- output was stub-identical zeros; shfl_xor is guaranteed)
//   store: per-reg scalar stores, 4 x 64B-line coalesced per wave instruction
// LDS swizzle phys = j ^ (((j>>10)&3)<<3) ^ (((j>>8)&3)<<2):
//   verified j=0x123->295, j=0xC05->3101 on both write and read sides.

typedef float f32x4 __attribute__((ext_vector_type(4)));

#define DPP_XOR(x, ctrl) \
    __int_as_float(__builtin_amdgcn_mov_dpp(__float_as_int(x), (ctrl), 0xF, 0xF, true))

__device__ __forceinline__ void wht16(float v[16]) {
#pragma unroll
    for (int h = 1; h < 16; h <<= 1) {
#pragma unroll
        for (int i = 0; i < 16; i++) {
            if ((i & h) == 0) {
                float a = v[i], b = v[i ^ h];
                v[i]     = a + b;
                v[i ^ h] = a - b;
            }
        }
    }
}

__global__ __launch_bounds__(256) void fwht4096_kernel(const float* __restrict__ in,
                                                       float* __restrict__ out) {
    __shared__ float lds[4096];   // 16 KB, no padding (XOR-swizzled)

    const int row = blockIdx.x;
    const int t   = threadIdx.x;
    const int l01 = t & 3, l23 = (t >> 2) & 3, l45 = (t >> 4) & 3, w = t >> 6;

    const float s1  = (t & 1)  ? -1.f : 1.f;
    const float s2  = (t & 2)  ? -1.f : 1.f;
    const float s16 = (t & 16) ? -1.f : 1.f;
    const float s32 = (t & 32) ? -1.f : 1.f;

    float v[16];

    // ---- load: contiguous 64B per thread, 4 x dwordx4 ----
    const f32x4* p4 = (const f32x4*)(in + (size_t)row * 4096 + t * 16);
#pragma unroll
    for (int q = 0; q < 4; q++) {
        f32x4 f = p4[q];
        v[4 * q + 0] = f.x; v[4 * q + 1] = f.y;
        v[4 * q + 2] = f.z; v[4 * q + 3] = f.w;
    }

    // ---- phase A: bits 0-3 in regs ----
    wht16(v);

    // bits 4-5: butterflies across lane bits 0-1 (DPP quad_perm, VALU pipe)
#pragma unroll
    for (int r = 0; r < 16; r++) {
        float p = DPP_XOR(v[r], 0xB1);          // xor lane^1
        v[r] = fmaf(s1, v[r], p);               // bit=0: v+p ; bit=1: p-v
    }
#pragma unroll
    for (int r = 0; r < 16; r++) {
        float p = DPP_XOR(v[r], 0x4E);          // xor lane^2
        v[r] = fmaf(s2, v[r], p);
    }

    // ---- LDS write: j = t*16 + rA, swizzled; 4 x ds_write_b128 ----
    {
        const int xw = ((w & 3) << 3) ^ ((l45 & 3) << 2);  // swizzle bits 2..4
        float* wrow  = &lds[(t ^ (xw >> 4)) * 16];
        const int bx = (xw >> 2) & 3;                      // 16B-block xor
#pragma unroll
        for (int a = 0; a < 4; a++) {
            f32x4 f = { v[4 * a + 0], v[4 * a + 1], v[4 * a + 2], v[4 * a + 3] };
            *(f32x4*)&wrow[4 * (a ^ bx)] = f;
        }
    }
    __syncthreads();

    // ---- LDS read: j' = l45*1024 + r*64 + w*16 + l23*4 + l01, same swizzle ----
    {
        const int low = w * 16 + l23 * 4 + l01;
#pragma unroll
        for (int g = 0; g < 4; g++) {
            const int base = l45 * 1024 + ((low ^ (l45 << 3)) ^ (g << 2));
#pragma unroll
            for (int i = 0; i < 4; i++) {
                const int r = 4 * g + i;
                v[r] = lds[base + r * 64];
            }
        }
    }

    // ---- phase B: bits 6-9 in regs ----
    wht16(v);

    // bit 10: butterfly across lane bit 4 via ds_swizzle xor16
#pragma unroll
    for (int r = 0; r < 16; r++) {
        float p = __int_as_float(
            __builtin_amdgcn_ds_swizzle(__float_as_int(v[r]), 0x401F));
        v[r] = fmaf(s16, v[r], p);
    }

    // bit 11: butterfly across lane bit 5 via __shfl_xor (guaranteed semantics)
#pragma unroll
    for (int r = 0; r < 16; r++) {
        float p = __shfl_xor(v[r], 32, 64);
        v[r] = fmaf(s32, v[r], p);
    }

    // ---- store: per reg r, wave covers 4 x 64B full lines ----
    float* ob = out + (size_t)row * 4096 + l45 * 1024 + w * 16 + l23 * 4 + l01;
#pragma unroll
    for (int r = 0; r < 16; r++) ob[r * 64] = v[r];
}

extern "C" void kernel_launch(void* const* d_in, const int* in_sizes, int n_in,
                              void* d_out, int out_size, void* d_ws, size_t ws_size,
                              hipStream_t stream) {
    const float* x = (const float*)d_in[0];
    float* out     = (float*)d_out;
    const int rows = in_sizes[0] / 4096;   // 16384
    fwht4096_kernel<<<dim3(rows), dim3(256), 0, stream>>>(x, out);
}